// Round 1
// baseline (356.194 us; speedup 1.0000x reference)
//
#include <hip/hip_runtime.h>
#include <hip/hip_bf16.h>

#define MAX_DIST 32.0f
#define BOX 129

// One thread per (point, feature) element. Lanes 0..31 of each half-wave
// handle one point: coalesced 128B feature read, 32 consecutive atomicAdds.
__global__ void __launch_bounds__(256) scatter_kernel(
    const float* __restrict__ coords,
    const float* __restrict__ features,
    float* __restrict__ grid,
    int N) {
  int total = N * 32;
  int stride = gridDim.x * blockDim.x;
  for (int t = blockIdx.x * blockDim.x + threadIdx.x; t < total; t += stride) {
    int p = t >> 5;
    int f = t & 31;
    float x = coords[3 * p + 0];
    float y = coords[3 * p + 1];
    float z = coords[3 * p + 2];
    // (c + 32) / 0.5 == (c + 32) * 2  (exact), round-half-even like jnp.round
    int gx = __float2int_rn((x + MAX_DIST) * 2.0f);
    int gy = __float2int_rn((y + MAX_DIST) * 2.0f);
    int gz = __float2int_rn((z + MAX_DIST) * 2.0f);
    if ((unsigned)gx < BOX && (unsigned)gy < BOX && (unsigned)gz < BOX) {
      long cell = ((long)gx * BOX + gy) * BOX + gz;
      atomicAdd(&grid[cell * 32 + f], features[(long)p * 32 + f]);
    }
  }
}

extern "C" void kernel_launch(void* const* d_in, const int* in_sizes, int n_in,
                              void* d_out, int out_size, void* d_ws, size_t ws_size,
                              hipStream_t stream) {
  const float* coords   = (const float*)d_in[0];
  const float* features = (const float*)d_in[1];
  float* grid = (float*)d_out;

  int N = in_sizes[0] / 3;  // 500000

  // Zero the whole output grid (harness poisons it with 0xAA every call).
  hipMemsetAsync(d_out, 0, (size_t)out_size * sizeof(float), stream);

  int total = N * 32;
  int block = 256;
  int grid_blocks = 4096;
  if (grid_blocks > (total + block - 1) / block)
    grid_blocks = (total + block - 1) / block;
  scatter_kernel<<<grid_blocks, block, 0, stream>>>(coords, features, grid, N);
}